// Round 8
// baseline (77.289 us; speedup 1.0000x reference)
//
#include <hip/hip_runtime.h>
#include <math.h>

typedef unsigned char u8;
typedef unsigned short u16;
typedef unsigned int u32;
typedef __attribute__((ext_vector_type(8))) int i32x8;
typedef __attribute__((ext_vector_type(4))) float f32x4;

#define SC1 0x7F7F7F7F   // e8m0 scale bytes = 127 -> 2^0 = 1.0

// ---------- helpers ----------

// order-preserving float -> uint mapping (monotonic), for atomicMax on floats
__device__ __forceinline__ u32 ordf(float f) {
    u32 u = __float_as_uint(f);
    return (u & 0x80000000u) ? ~u : (u | 0x80000000u);
}
__device__ __forceinline__ float unordf(u32 u) {
    u = (u & 0x80000000u) ? (u & 0x7FFFFFFFu) : ~u;
    return __uint_as_float(u);
}

// f32 -> OCP e4m3fn with RNE. Assumes finite |x| <= 1.
__device__ __forceinline__ u32 f2e4m3(float x) {
    u32 u = __float_as_uint(x);
    u32 sgn = (u >> 24) & 0x80u;
    int ne = (int)((u >> 23) & 0xFF) - 120;   // e4m3 biased exponent
    if (ne >= 1) {
        u32 m = u & 0x7FFFFFu;
        u32 keep = m >> 20;
        u32 rest = m & 0xFFFFFu;
        keep += (rest > 0x80000u) || (rest == 0x80000u && (keep & 1u));
        if (keep == 8u) { keep = 0u; ne += 1; }
        return sgn | ((u32)ne << 3) | keep;
    }
    // subnormal: multiples of 2^-9
    float ax = __uint_as_float(u & 0x7FFFFFFFu);
    u32 f = (u32)__builtin_rintf(ax * 512.0f);
    if (f >= 8u) return sgn | 0x08u;          // rounds up to 2^-6 normal
    return sgn | f;
}

// async global->LDS, 16B per lane (dest = wave-uniform base + lane*16)
__device__ __forceinline__ void gload_lds16(const void* gsrc, void* ldst) {
    __builtin_amdgcn_global_load_lds(
        (const __attribute__((address_space(1))) void*)gsrc,
        (__attribute__((address_space(3))) void*)ldst,
        16, 0, 0);
}

__device__ __forceinline__ i32x8 ldfrag(const char* plo, const char* phi) {
    int4 lo = *(const int4*)plo;
    int4 hi = *(const int4*)phi;
    i32x8 r = {lo.x, lo.y, lo.z, lo.w, hi.x, hi.y, hi.z, hi.w};
    return r;
}

#define BARRIER do { __builtin_amdgcn_sched_barrier(0); \
                     __builtin_amdgcn_s_barrier(); \
                     __builtin_amdgcn_sched_barrier(0); } while (0)
#define VMCNT(n) do { asm volatile("s_waitcnt vmcnt(" #n ")" ::: "memory"); \
                      __builtin_amdgcn_sched_barrier(0); } while (0)

// ---------- kernel 1: normalize rows -> fp8 e4m3; init rowmax ----------
// one wave per row; lane handles 8 consecutive floats (D=512 = 64*8)

__global__ __launch_bounds__(256) void norm_kernel(
    const float* __restrict__ feat, const float* __restrict__ memf,
    u8* __restrict__ fb, u8* __restrict__ mb, u32* __restrict__ rowmax,
    int N, int M, int D)
{
    const int lane = threadIdx.x & 63;
    const int wid  = threadIdx.x >> 6;
    const int rid  = blockIdx.x * 4 + wid;
    if (rid >= N + M) return;

    const float* src;
    u8* dst;
    if (rid < N) { src = feat + (size_t)rid * D; dst = fb + (size_t)rid * D; }
    else         { src = memf + (size_t)(rid - N) * D; dst = mb + (size_t)(rid - N) * D; }

    float4 v0 = *(const float4*)(src + lane * 8);
    float4 v1 = *(const float4*)(src + lane * 8 + 4);
    float ss = v0.x*v0.x + v0.y*v0.y + v0.z*v0.z + v0.w*v0.w
             + v1.x*v1.x + v1.y*v1.y + v1.z*v1.z + v1.w*v1.w;
    #pragma unroll
    for (int m = 1; m <= 32; m <<= 1) ss += __shfl_xor(ss, m);

    float inv = 1.0f / fmaxf(sqrtf(ss), 1e-8f);

    u32 w0 =  f2e4m3(v0.x * inv)        | (f2e4m3(v0.y * inv) << 8)
           | (f2e4m3(v0.z * inv) << 16) | (f2e4m3(v0.w * inv) << 24);
    u32 w1 =  f2e4m3(v1.x * inv)        | (f2e4m3(v1.y * inv) << 8)
           | (f2e4m3(v1.z * inv) << 16) | (f2e4m3(v1.w * inv) << 24);
    *(uint2*)(dst + lane * 8) = make_uint2(w0, w1);

    if (rid < N && lane == 0) rowmax[rid] = 0u;   // below any real sim
}

// ---------- kernel 2: 128x128x(BK=128 fp8) MX-fp8 GEMM + fused row-max ----
// m97/m148-style: single-buffered LDS (32KB), 2 barriers per K-tile, grid
// 4096 blocks -> ~3 blocks/CU co-resident; inter-block TLP hides the
// vmcnt(0) barrier drains that intra-block scheduling could not (r2-r6).
// 4 waves (2x2), each wave 64x64 out = acc[4][4] 16x16 frags.
// MFMA: mfma_scale_f32_16x16x128_f8f6f4, fmt=0 (e4m3), scales = 1.0.
// LDS: A[128][128B] @0, B[128][128B] @16KB. 128B rows, XOR swizzle
// byte ^= ((row&7)<<4) via pre-swizzled global source, linear gload dest.
// Frag: lane l: row=l&15, k-bytes (l>>4)*32 + [0..31] = 2 x b128 reads.

#define STAGEA(t, p) gload_lds16(gA + (size_t)((p) * 32) * D + (t) * 128, \
                                 &L[(p) * 4096 + tid * 16])
#define STAGEB(t, p) gload_lds16(gB + (size_t)((p) * 32) * D + (t) * 128, \
                                 &L[16384 + (p) * 4096 + tid * 16])
#define STAGE_ALL(t) do { STAGEA(t,0); STAGEA(t,1); STAGEA(t,2); STAGEA(t,3); \
                          STAGEB(t,0); STAGEB(t,1); STAGEB(t,2); STAGEB(t,3); } while (0)

__global__ __launch_bounds__(256, 3) void gemm_max_kernel(
    const u8* __restrict__ fb, const u8* __restrict__ mb,
    u32* __restrict__ rowmax, int N, int M, int D)
{
    __shared__ __align__(16) u8 L[32768];   // 32 KB, single-buffered

    const int tid  = threadIdx.x;
    const int lane = tid & 63;
    const int wid  = tid >> 6;
    const int wwr  = wid >> 1;      // 0..1 wave row
    const int wwc  = wid & 1;       // 0..1 wave col
    const int l15  = lane & 15;
    const int l4   = lane >> 4;
    const int n0   = blockIdx.y * 128;
    const int m0   = blockIdx.x * 128;
    const int nt   = D >> 7;        // K-tiles of 128 (D=512 -> 4)

    // staging: per-thread pre-swizzled global bases (row = t8, chunk = tid&7)
    const int t8   = tid >> 3;
    const int swz  = ((tid & 7) ^ (t8 & 7)) * 16;
    const u8* gA = fb + (size_t)(n0 + t8) * D + swz;
    const u8* gB = mb + (size_t)(m0 + t8) * D + swz;

    // ds_read: per-lane swizzled k-offsets (two b128 per frag)
    const int s    = (l15 & 7) << 4;
    const int oLo  = (l4 * 32) ^ s;
    const int oHi  = (l4 * 32 + 16) ^ s;
    const char* Lb = (const char*)L;
    const char* Ab = Lb + (wwr * 64 + l15) * 128;           // A row base
    const char* Bb = Lb + 16384 + (wwc * 64 + l15) * 128;   // B row base

    f32x4 acc[4][4] = {};
    i32x8 af[4], bf[4];

    // ---- prologue: stage tile0, drain, barrier ----
    STAGE_ALL(0);
    VMCNT(0);
    BARRIER;

    for (int u = 0; u < nt; ++u) {
        // ---- read 8 frag-pairs (16 x b128); compiler schedules lgkm ----
        #pragma unroll
        for (int i = 0; i < 4; ++i)
            af[i] = ldfrag(Ab + i * 2048 + oLo, Ab + i * 2048 + oHi);
        #pragma unroll
        for (int j = 0; j < 4; ++j)
            bf[j] = ldfrag(Bb + j * 2048 + oLo, Bb + j * 2048 + oHi);

        // ---- 16 MFMA (all frags consumed -> lgkm drained before barrier) ----
        __builtin_amdgcn_s_setprio(1);
        #pragma unroll
        for (int i = 0; i < 4; ++i)
            #pragma unroll
            for (int j = 0; j < 4; ++j)
                acc[i][j] = __builtin_amdgcn_mfma_scale_f32_16x16x128_f8f6f4(
                    af[i], bf[j], acc[i][j], 0, 0, 0, SC1, 0, SC1);
        __builtin_amdgcn_s_setprio(0);
        BARRIER;                       // all waves done reading this tile

        // ---- stage next tile into the same buffer; drain; barrier ----
        if (u + 1 < nt) {
            STAGE_ALL(u + 1);
            VMCNT(0);
            BARRIER;
        }
    }

    // ---- epilogue: per-row max; cross-wave LDS reduce; one atomic/row ----
    BARRIER;                          // protect L reuse
    float* red = (float*)L;           // [128][2]
    #pragma unroll
    for (int i = 0; i < 4; ++i) {
        #pragma unroll
        for (int rr = 0; rr < 4; ++rr) {
            float v = fmaxf(fmaxf(acc[i][0][rr], acc[i][1][rr]),
                            fmaxf(acc[i][2][rr], acc[i][3][rr]));
            v = fmaxf(v, __shfl_xor(v, 1));
            v = fmaxf(v, __shfl_xor(v, 2));
            v = fmaxf(v, __shfl_xor(v, 4));
            v = fmaxf(v, __shfl_xor(v, 8));
            if (l15 == 0) {
                int rloc = wwr * 64 + i * 16 + l4 * 4 + rr;
                red[rloc * 2 + wwc] = v;
            }
        }
    }
    __syncthreads();
    if (tid < 128) {
        float v = fmaxf(red[tid * 2 + 0], red[tid * 2 + 1]);
        atomicMax(&rowmax[n0 + tid], ordf(v));
    }
}

// ---------- kernel 3: BCE + novelty weight + mean ----------

__global__ __launch_bounds__(1024) void finalize_kernel(
    const float* __restrict__ pred, const float* __restrict__ targ,
    const u32* __restrict__ rowmax, float* __restrict__ out, int N)
{
    __shared__ float wsum[16];
    const int tid = threadIdx.x;
    const int lane = tid & 63;
    const int wid = tid >> 6;

    float sacc = 0.f;
    for (int i = tid; i < N; i += 1024) {
        float x = pred[i];
        float t = targ[i];
        float bl = fmaxf(x, 0.f) + log1pf(expf(-fabsf(x))) - x * t;  // softplus(x) - x*t
        float ms = unordf(rowmax[i]);
        float w = 1.0f + 2.0f * (1.0f - ms);
        sacc += bl * w;
    }
    #pragma unroll
    for (int m = 1; m <= 32; m <<= 1) sacc += __shfl_xor(sacc, m);
    if (lane == 0) wsum[wid] = sacc;
    __syncthreads();
    if (tid < 16) {
        float t = wsum[tid];
        t += __shfl_xor(t, 1);
        t += __shfl_xor(t, 2);
        t += __shfl_xor(t, 4);
        t += __shfl_xor(t, 8);
        if (tid == 0) out[0] = t / (float)N;
    }
}

// ---------- launch ----------

extern "C" void kernel_launch(void* const* d_in, const int* in_sizes, int n_in,
                              void* d_out, int out_size, void* d_ws, size_t ws_size,
                              hipStream_t stream) {
    const float* pred = (const float*)d_in[0];
    const float* targ = (const float*)d_in[1];
    const float* feat = (const float*)d_in[2];
    const float* memf = (const float*)d_in[3];
    const int N = in_sizes[0];
    const int D = in_sizes[2] / N;
    const int M = in_sizes[3] / D;
    float* out = (float*)d_out;

    u8* fb8 = (u8*)d_ws;                           // N*D fp8
    u8* mb8 = fb8 + (size_t)N * D;                 // M*D fp8
    u32* rowmax = (u32*)(mb8 + (size_t)M * D);     // N u32

    const int rows = N + M;
    norm_kernel<<<dim3((rows + 3) / 4), dim3(256), 0, stream>>>(
        feat, memf, fb8, mb8, rowmax, N, M, D);
    gemm_max_kernel<<<dim3(M / 128, N / 128), dim3(256), 0, stream>>>(
        fb8, mb8, rowmax, N, M, D);
    finalize_kernel<<<dim3(1), dim3(1024), 0, stream>>>(pred, targ, rowmax, out, N);
}

// Round 9
// 50.199 us; speedup vs baseline: 1.5397x; 1.5397x over previous
//
#include <hip/hip_runtime.h>
#include <math.h>

typedef unsigned char u8;
typedef unsigned short u16;
typedef unsigned int u32;
typedef __attribute__((ext_vector_type(8))) int i32x8;
typedef __attribute__((ext_vector_type(4))) float f32x4;

#define SC1 0x7F7F7F7F   // e8m0 scale bytes = 127 -> 2^0 = 1.0
#define CPB 1024         // cols per block
#define NCT (CPB / 128)  // col-tiles per block = 8

// ---------- helpers ----------

__device__ __forceinline__ u32 ordf(float f) {
    u32 u = __float_as_uint(f);
    return (u & 0x80000000u) ? ~u : (u | 0x80000000u);
}
__device__ __forceinline__ float unordf(u32 u) {
    u = (u & 0x80000000u) ? (u & 0x7FFFFFFFu) : ~u;
    return __uint_as_float(u);
}

// f32 -> OCP e4m3fn with RNE. Assumes finite |x| <= 1.
__device__ __forceinline__ u32 f2e4m3(float x) {
    u32 u = __float_as_uint(x);
    u32 sgn = (u >> 24) & 0x80u;
    int ne = (int)((u >> 23) & 0xFF) - 120;   // e4m3 biased exponent
    if (ne >= 1) {
        u32 m = u & 0x7FFFFFu;
        u32 keep = m >> 20;
        u32 rest = m & 0xFFFFFu;
        keep += (rest > 0x80000u) || (rest == 0x80000u && (keep & 1u));
        if (keep == 8u) { keep = 0u; ne += 1; }
        return sgn | ((u32)ne << 3) | keep;
    }
    float ax = __uint_as_float(u & 0x7FFFFFFFu);
    u32 f = (u32)__builtin_rintf(ax * 512.0f);
    if (f >= 8u) return sgn | 0x08u;
    return sgn | f;
}

// async global->LDS, 16B per lane (dest = wave-uniform base + lane*16)
__device__ __forceinline__ void gload_lds16(const void* gsrc, void* ldst) {
    __builtin_amdgcn_global_load_lds(
        (const __attribute__((address_space(1))) void*)gsrc,
        (__attribute__((address_space(3))) void*)ldst,
        16, 0, 0);
}

__device__ __forceinline__ i32x8 ldfrag(const char* plo, const char* phi) {
    int4 lo = *(const int4*)plo;
    int4 hi = *(const int4*)phi;
    i32x8 r = {lo.x, lo.y, lo.z, lo.w, hi.x, hi.y, hi.z, hi.w};
    return r;
}

#define BARRIER do { __builtin_amdgcn_sched_barrier(0); \
                     __builtin_amdgcn_s_barrier(); \
                     __builtin_amdgcn_sched_barrier(0); } while (0)
#define VMCNT(n) do { asm volatile("s_waitcnt vmcnt(" #n ")" ::: "memory"); \
                      __builtin_amdgcn_sched_barrier(0); } while (0)

// ---------- kernel 1: normalize rows -> fp8 e4m3; init rowmax ----------

__global__ __launch_bounds__(256) void norm_kernel(
    const float* __restrict__ feat, const float* __restrict__ memf,
    u8* __restrict__ fb, u8* __restrict__ mb, u32* __restrict__ rowmax,
    int N, int M, int D)
{
    const int lane = threadIdx.x & 63;
    const int wid  = threadIdx.x >> 6;
    const int rid  = blockIdx.x * 4 + wid;
    if (rid >= N + M) return;

    const float* src;
    u8* dst;
    if (rid < N) { src = feat + (size_t)rid * D; dst = fb + (size_t)rid * D; }
    else         { src = memf + (size_t)(rid - N) * D; dst = mb + (size_t)(rid - N) * D; }

    float4 v0 = *(const float4*)(src + lane * 8);
    float4 v1 = *(const float4*)(src + lane * 8 + 4);
    float ss = v0.x*v0.x + v0.y*v0.y + v0.z*v0.z + v0.w*v0.w
             + v1.x*v1.x + v1.y*v1.y + v1.z*v1.z + v1.w*v1.w;
    #pragma unroll
    for (int m = 1; m <= 32; m <<= 1) ss += __shfl_xor(ss, m);

    float inv = 1.0f / fmaxf(sqrtf(ss), 1e-8f);

    u32 w0 =  f2e4m3(v0.x * inv)        | (f2e4m3(v0.y * inv) << 8)
           | (f2e4m3(v0.z * inv) << 16) | (f2e4m3(v0.w * inv) << 24);
    u32 w1 =  f2e4m3(v1.x * inv)        | (f2e4m3(v1.y * inv) << 8)
           | (f2e4m3(v1.z * inv) << 16) | (f2e4m3(v1.w * inv) << 24);
    *(uint2*)(dst + lane * 8) = make_uint2(w0, w1);

    if (rid < N && lane == 0) rowmax[rid] = 0u;   // below any real sim
}

// ---------- kernel 2: A-in-registers MX-fp8 GEMM + fused row-max ----------
// Block = 128-row stripe x 1024 cols (8 col-tiles of 128). Grid 512 = 2/CU.
// Per wave (2x2): A 64 rows x K=512 held ENTIRELY in regs: areg[4][4] i32x8
// (128 VGPR) -> zero LDS traffic for A. B: 64KB tile (4 kt x [128 rows][128B])
// staged per col-tile via gload_lds (single-buffered), frags read via XOR-
// swizzled b128 pairs (r7/r8-verified layout). Per-ct epilogue folds acc into
// a running vmax and resets acc. LDS read traffic: 2x lower than r8.
// MFMA: mfma_scale_f32_16x16x128_f8f6f4, fmt=0 (e4m3), scales = 1.0.

#define STAGE_B(gB) do { \
    _Pragma("unroll") \
    for (int kt_ = 0; kt_ < 4; ++kt_) \
      _Pragma("unroll") \
      for (int p_ = 0; p_ < 4; ++p_) \
        gload_lds16((gB) + (size_t)(p_ * 32) * D + kt_ * 128, \
                    &L[kt_ * 16384 + p_ * 4096 + tid * 16]); \
  } while (0)

__global__ __launch_bounds__(256, 2) void gemm_max_kernel(
    const u8* __restrict__ fb, const u8* __restrict__ mb,
    u32* __restrict__ rowmax, int N, int M, int D)
{
    __shared__ __align__(16) u8 L[65536];   // B tile only

    const int tid  = threadIdx.x;
    const int lane = tid & 63;
    const int wid  = tid >> 6;
    const int wwr  = wid >> 1;      // A row-half (0..1)
    const int wwc  = wid & 1;       // B col-half (0..1)
    const int l15  = lane & 15;
    const int l4   = lane >> 4;
    const int n0   = blockIdx.y * 128;
    const int m0   = blockIdx.x * CPB;

    // B staging: per-thread pre-swizzled global base (row = t8, chunk = tid&7)
    const int t8   = tid >> 3;
    const int swz  = ((tid & 7) ^ (t8 & 7)) * 16;

    // B ds_read: per-lane swizzled k-offsets (two b128 per frag)
    const int s    = (l15 & 7) << 4;
    const int oLo  = (l4 * 32) ^ s;
    const int oHi  = (l4 * 32 + 16) ^ s;
    const char* Lb = (const char*)L;
    const char* Bbase = Lb + (wwc * 64 + l15) * 128;   // + kt*16384 + j*2048

    // ---- prologue: issue B stage for ct=0, then load A stripe into regs ----
    const u8* gB0 = mb + (size_t)(m0 + t8) * D + swz;
    STAGE_B(gB0);

    const u8* gArow = fb + (size_t)(n0 + wwr * 64 + l15) * D + l4 * 32;
    i32x8 areg[4][4];   // [row-frag i][k-tile kt], 128 VGPR
    #pragma unroll
    for (int i = 0; i < 4; ++i)
        #pragma unroll
        for (int kt = 0; kt < 4; ++kt)
            areg[i][kt] = *(const i32x8*)(gArow + (size_t)(i * 16) * D + kt * 128);

    VMCNT(0);
    BARRIER;

    f32x4 acc[4][4] = {};
    float vmax[4][4];
    #pragma unroll
    for (int i = 0; i < 4; ++i)
        #pragma unroll
        for (int rr = 0; rr < 4; ++rr) vmax[i][rr] = -1e30f;

    for (int ct = 0; ct < NCT; ++ct) {
        if (ct > 0) {
            BARRIER;   // all waves done reading previous B tile (lgkm-certified)
            const u8* gB = mb + (size_t)(m0 + ct * 128 + t8) * D + swz;
            STAGE_B(gB);
            VMCNT(0);
            BARRIER;
        }

        // ---- compute: 4 k-tiles x (4 B-frag reads + 16 MFMA) ----
        #pragma unroll
        for (int kt = 0; kt < 4; ++kt) {
            #pragma unroll
            for (int j = 0; j < 4; ++j) {
                i32x8 bfj = ldfrag(Bbase + kt * 16384 + j * 2048 + oLo,
                                   Bbase + kt * 16384 + j * 2048 + oHi);
                #pragma unroll
                for (int i = 0; i < 4; ++i)
                    acc[i][j] = __builtin_amdgcn_mfma_scale_f32_16x16x128_f8f6f4(
                        areg[i][kt], bfj, acc[i][j], 0, 0, 0, SC1, 0, SC1);
            }
        }

        // ---- fold this col-tile's sims into running max; reset acc ----
        #pragma unroll
        for (int i = 0; i < 4; ++i)
            #pragma unroll
            for (int rr = 0; rr < 4; ++rr) {
                float v = fmaxf(fmaxf(acc[i][0][rr], acc[i][1][rr]),
                                fmaxf(acc[i][2][rr], acc[i][3][rr]));
                vmax[i][rr] = fmaxf(vmax[i][rr], v);
            }
        #pragma unroll
        for (int i = 0; i < 4; ++i)
            #pragma unroll
            for (int j = 0; j < 4; ++j) acc[i][j] = (f32x4)0.0f;
    }

    // ---- epilogue: cross-lane + cross-wave max reduce; one atomic/row ----
    BARRIER;                      // protect L reuse
    float* red = (float*)L;       // [128][2]
    #pragma unroll
    for (int i = 0; i < 4; ++i) {
        #pragma unroll
        for (int rr = 0; rr < 4; ++rr) {
            float v = vmax[i][rr];
            v = fmaxf(v, __shfl_xor(v, 1));
            v = fmaxf(v, __shfl_xor(v, 2));
            v = fmaxf(v, __shfl_xor(v, 4));
            v = fmaxf(v, __shfl_xor(v, 8));
            if (l15 == 0) {
                int rloc = wwr * 64 + i * 16 + l4 * 4 + rr;
                red[rloc * 2 + wwc] = v;
            }
        }
    }
    __syncthreads();
    if (tid < 128) {
        float v = fmaxf(red[tid * 2 + 0], red[tid * 2 + 1]);
        atomicMax(&rowmax[n0 + tid], ordf(v));
    }
}

// ---------- kernel 3a: BCE + novelty weight, per-block partial sums ----------

__global__ __launch_bounds__(256) void finalize1_kernel(
    const float* __restrict__ pred, const float* __restrict__ targ,
    const u32* __restrict__ rowmax, float* __restrict__ partial, int N)
{
    __shared__ float ws4[4];
    const int tid = threadIdx.x;
    const int i = blockIdx.x * 256 + tid;

    float sv = 0.f;
    if (i < N) {
        float x = pred[i];
        float t = targ[i];
        float bl = fmaxf(x, 0.f) + log1pf(expf(-fabsf(x))) - x * t;
        float ms = unordf(rowmax[i]);
        sv = bl * (1.0f + 2.0f * (1.0f - ms));
    }
    #pragma unroll
    for (int m = 1; m <= 32; m <<= 1) sv += __shfl_xor(sv, m);
    if ((tid & 63) == 0) ws4[tid >> 6] = sv;
    __syncthreads();
    if (tid == 0) partial[blockIdx.x] = ws4[0] + ws4[1] + ws4[2] + ws4[3];
}

// ---------- kernel 3b: final reduce ----------

__global__ __launch_bounds__(64) void finalize2_kernel(
    const float* __restrict__ partial, float* __restrict__ out, int nb, int N)
{
    float sv = 0.f;
    for (int i = threadIdx.x; i < nb; i += 64) sv += partial[i];
    #pragma unroll
    for (int m = 1; m <= 32; m <<= 1) sv += __shfl_xor(sv, m);
    if (threadIdx.x == 0) out[0] = sv / (float)N;
}

// ---------- launch ----------

extern "C" void kernel_launch(void* const* d_in, const int* in_sizes, int n_in,
                              void* d_out, int out_size, void* d_ws, size_t ws_size,
                              hipStream_t stream) {
    const float* pred = (const float*)d_in[0];
    const float* targ = (const float*)d_in[1];
    const float* feat = (const float*)d_in[2];
    const float* memf = (const float*)d_in[3];
    const int N = in_sizes[0];
    const int D = in_sizes[2] / N;
    const int M = in_sizes[3] / D;
    float* out = (float*)d_out;

    u8* fb8 = (u8*)d_ws;                           // N*D fp8
    u8* mb8 = fb8 + (size_t)N * D;                 // M*D fp8
    u32* rowmax = (u32*)(mb8 + (size_t)M * D);     // N u32
    float* partial = (float*)(rowmax + N);         // nb floats

    const int rows = N + M;
    const int nb = (N + 255) / 256;
    norm_kernel<<<dim3((rows + 3) / 4), dim3(256), 0, stream>>>(
        feat, memf, fb8, mb8, rowmax, N, M, D);
    gemm_max_kernel<<<dim3(M / CPB, N / 128), dim3(256), 0, stream>>>(
        fb8, mb8, rowmax, N, M, D);
    finalize1_kernel<<<dim3(nb), dim3(256), 0, stream>>>(
        pred, targ, rowmax, partial, N);
    finalize2_kernel<<<dim3(1), dim3(64), 0, stream>>>(partial, out, nb, N);
}